// Round 1
// baseline (678.298 us; speedup 1.0000x reference)
//
#include <hip/hip_runtime.h>
#include <math.h>

// Problem constants: B=16, S=256 -> N=4096 tokens; D=256; U=2000.
#define N_TOK 4096
#define DIM   256
#define NURL  2000
#define TCH   4     // tokens processed per chunk (per trans[u] stream)

// Workspace layout (int32 entries; total 10240 ints = 40 KB):
#define WS_COUNTS 0      // [2000]  tokens per url
#define WS_OFFS   2048   // [2000]  exclusive prefix (bucket start per url)
#define WS_CURS   4096   // [2000]  scatter cursor (init = offs)
#define WS_BUCKET 6144   // [4096]  token ids grouped by url

// ---------------- pass 1: zero counts ----------------
__global__ __launch_bounds__(256) void zero_k(int* __restrict__ ws) {
    const int i = blockIdx.x * 256 + threadIdx.x;
    if (i < NURL) ws[WS_COUNTS + i] = 0;
}

// ---------------- pass 2: histogram ----------------
__global__ __launch_bounds__(256) void hist_k(const int* __restrict__ urls,
                                              int* __restrict__ ws) {
    const int n = blockIdx.x * 256 + threadIdx.x;   // grid covers exactly N_TOK
    atomicAdd(&ws[WS_COUNTS + urls[n]], 1);
}

// ---------------- pass 3: exclusive scan (1 wave; lane handles 32 urls) ----
__global__ __launch_bounds__(64) void scan_k(int* __restrict__ ws) {
    const int lane = threadIdx.x;
    const int base = lane * 32;                      // 64*32 = 2048 >= 2000
    int c[32];
    int local = 0;
#pragma unroll
    for (int i = 0; i < 32; ++i) {
        const int u = base + i;
        c[i] = (u < NURL) ? ws[WS_COUNTS + u] : 0;
        local += c[i];
    }
    // inclusive scan across 64 lanes, then make exclusive
    int x = local;
    for (int off = 1; off < 64; off <<= 1) {
        const int y = __shfl_up(x, off);
        if (lane >= off) x += y;
    }
    int run = x - local;
#pragma unroll
    for (int i = 0; i < 32; ++i) {
        const int u = base + i;
        if (u < NURL) { ws[WS_OFFS + u] = run; ws[WS_CURS + u] = run; }
        run += c[i];
    }
}

// ---------------- pass 4: scatter token ids into url buckets ----------------
__global__ __launch_bounds__(256) void scatter_k(const int* __restrict__ urls,
                                                 int* __restrict__ ws) {
    const int n = blockIdx.x * 256 + threadIdx.x;
    const int u = urls[n];
    const int pos = atomicAdd(&ws[WS_CURS + u], 1);
    ws[WS_BUCKET + pos] = n;
}

// ---------------- pass 5: compute ----------------
// One 256-thread block (4 waves) per url. Waves split the 256 d_in rows
// (64 each); up to TCH=4 tokens share each trans-row load (16 FMAs / 16 B).
// Cross-wave partials reduced through LDS; wave k finalizes token k.
#define FMA4(acc, xv, tv)                 \
    acc.x = fmaf((xv), (tv).x, acc.x);    \
    acc.y = fmaf((xv), (tv).y, acc.y);    \
    acc.z = fmaf((xv), (tv).z, acc.z);    \
    acc.w = fmaf((xv), (tv).w, acc.w);

__global__ __launch_bounds__(256) void compute_k(
    const float* __restrict__ inp,    // [N, D]
    const float* __restrict__ trans,  // [U, D, D]
    const float* __restrict__ bias,   // [U, D]
    const int*   __restrict__ ws,
    float*       __restrict__ out)    // [N, D]
{
    const int u   = blockIdx.x;
    const int cnt = ws[WS_COUNTS + u];
    if (cnt == 0) return;
    const int start = ws[WS_OFFS + u];
    const int tid  = threadIdx.x;
    const int wave = tid >> 6;
    const int lane = tid & 63;

    __shared__ __align__(16) float xs[TCH][DIM];        // 4 KB
    __shared__ __align__(16) float part[4][TCH][DIM];   // 16 KB
    __shared__ __align__(16) float bs[DIM];             // 1 KB
    __shared__ int toks[TCH];

    if (tid < 64) {
        reinterpret_cast<float4*>(bs)[tid] =
            reinterpret_cast<const float4*>(bias + (size_t)u * DIM)[tid];
    }

    const float4* T4 =
        reinterpret_cast<const float4*>(trans + (size_t)u * DIM * DIM) + lane;

    for (int c0 = 0; c0 < cnt; c0 += TCH) {
        const int nk = min(TCH, cnt - c0);

        // stage x for the chunk's tokens: thread group k (64 threads) loads token k
        if (tid < nk * 64) {
            const int k = tid >> 6, l = tid & 63;
            const int tok = ws[WS_BUCKET + start + c0 + k];
            if (l == 0) toks[k] = tok;
            reinterpret_cast<float4*>(xs[k])[l] =
                reinterpret_cast<const float4*>(inp + (size_t)tok * DIM)[l];
        }
        __syncthreads();

        float4 a0 = {0,0,0,0}, a1 = {0,0,0,0}, a2 = {0,0,0,0}, a3 = {0,0,0,0};
        const int dbase = wave * 64;
#pragma unroll 2
        for (int d0 = 0; d0 < 64; d0 += 4) {
            const int d = dbase + d0;
            // x values broadcast from LDS (same-address, conflict-free), 4 rows at a time
            const float4 x0 = *reinterpret_cast<const float4*>(&xs[0][d]);
            const float4 x1 = *reinterpret_cast<const float4*>(&xs[1][d]);
            const float4 x2 = *reinterpret_cast<const float4*>(&xs[2][d]);
            const float4 x3 = *reinterpret_cast<const float4*>(&xs[3][d]);
            const float4 t0 = T4[(size_t)(d + 0) * (DIM / 4)];
            const float4 t1 = T4[(size_t)(d + 1) * (DIM / 4)];
            const float4 t2 = T4[(size_t)(d + 2) * (DIM / 4)];
            const float4 t3 = T4[(size_t)(d + 3) * (DIM / 4)];
            FMA4(a0, x0.x, t0) FMA4(a0, x0.y, t1) FMA4(a0, x0.z, t2) FMA4(a0, x0.w, t3)
            FMA4(a1, x1.x, t0) FMA4(a1, x1.y, t1) FMA4(a1, x1.z, t2) FMA4(a1, x1.w, t3)
            FMA4(a2, x2.x, t0) FMA4(a2, x2.y, t1) FMA4(a2, x2.z, t2) FMA4(a2, x2.w, t3)
            FMA4(a3, x3.x, t0) FMA4(a3, x3.y, t1) FMA4(a3, x3.z, t2) FMA4(a3, x3.w, t3)
        }

        reinterpret_cast<float4*>(part[wave][0])[lane] = a0;
        reinterpret_cast<float4*>(part[wave][1])[lane] = a1;
        reinterpret_cast<float4*>(part[wave][2])[lane] = a2;
        reinterpret_cast<float4*>(part[wave][3])[lane] = a3;
        __syncthreads();

        // wave k reduces + finalizes token k
        if (wave < nk) {
            const float4 p0 = reinterpret_cast<const float4*>(part[0][wave])[lane];
            const float4 p1 = reinterpret_cast<const float4*>(part[1][wave])[lane];
            const float4 p2 = reinterpret_cast<const float4*>(part[2][wave])[lane];
            const float4 p3 = reinterpret_cast<const float4*>(part[3][wave])[lane];
            const float4 b4 = reinterpret_cast<const float4*>(bs)[lane];
            float4 o;
            o.x = tanhf(p0.x + p1.x + p2.x + p3.x + b4.x);
            o.y = tanhf(p0.y + p1.y + p2.y + p3.y + b4.y);
            o.z = tanhf(p0.z + p1.z + p2.z + p3.z + b4.z);
            o.w = tanhf(p0.w + p1.w + p2.w + p3.w + b4.w);
            reinterpret_cast<float4*>(out + (size_t)toks[wave] * DIM)[lane] = o;
        }
        __syncthreads();  // protect xs/part before next chunk
    }
}

extern "C" void kernel_launch(void* const* d_in, const int* in_sizes, int n_in,
                              void* d_out, int out_size, void* d_ws, size_t ws_size,
                              hipStream_t stream) {
    const float* inp   = (const float*)d_in[0];  // [B,S,D] f32
    const int*   urls  = (const int*)  d_in[1];  // [B,S]   i32
    const float* trans = (const float*)d_in[2];  // [U,D,D] f32
    const float* bias  = (const float*)d_in[3];  // [U,D]   f32
    float*       out   = (float*)d_out;
    int*         ws    = (int*)d_ws;             // needs 40 KB

    zero_k<<<(NURL + 255) / 256, 256, 0, stream>>>(ws);
    hist_k<<<N_TOK / 256, 256, 0, stream>>>(urls, ws);
    scan_k<<<1, 64, 0, stream>>>(ws);
    scatter_k<<<N_TOK / 256, 256, 0, stream>>>(urls, ws);
    compute_k<<<NURL, 256, 0, stream>>>(inp, trans, bias, ws, out);
}